// Round 10
// baseline (1565.979 us; speedup 1.0000x reference)
//
#include <hip/hip_runtime.h>

#define NDIM  2048
#define NBAND 32               // 32 bands of 64 rows; 16 waves x 2 bands each
#define BCOLS 2176             // 0..2048 valid + pad
#define SLOTS 2128             // 2112 steps + pad
#define ENCB  0x40000000
#define SENTV 0xFFFFFFFFFFFFFFFFull

typedef unsigned long long u64;

// Static scratch: prep kernels rewrite everything main relies on, every launch.
__device__ __align__(16) float4 g_S4[(size_t)NBAND * SLOTS * 64];
__device__ __align__(16) u64    g_B[(size_t)(NBAND+1) * BCOLS * 2]; // boundary handoff

__device__ __forceinline__ u64 ald(const u64* p) {
  return __hip_atomic_load(p, __ATOMIC_RELAXED, __HIP_MEMORY_SCOPE_AGENT);
}
__device__ __forceinline__ void ast(u64* p, u64 v) {
  __hip_atomic_store(p, v, __ATOMIC_RELAXED, __HIP_MEMORY_SCOPE_AGENT);
}
// shift-up-by-1 across the wave via DPP wave_shr1. Lane 0 receives 0 and is
// overwritten by the boundary select.
__device__ __forceinline__ float shup1(float x) {
  int v = __builtin_amdgcn_update_dpp(0, __float_as_int(x), 0x138, 0xf, 0xf, false);
  return __int_as_float(v);
}
// global -> LDS direct DMA, 16B per lane. LDS dest is the WAVE-UNIFORM base.
typedef const __attribute__((address_space(1))) void GV;
typedef __attribute__((address_space(3)))       void LV;
__device__ __forceinline__ void gll16(const void* g, void* l) {
  __builtin_amdgcn_global_load_lds((GV*)g, (LV*)l, 16, 0, 0);
}

// ---------------- prep A: exp(theta) transposed into staircase order --------
__global__ void vit_prep_theta(const float* __restrict__ theta) {
  const int tid = blockIdx.x * blockDim.x + threadIdx.x;
  const int stride = gridDim.x * blockDim.x;
  const int total = NBAND * SLOTS * 64;
  for (int i = tid; i < total; i += stride) {
    const int l    = i & 63;
    const int rest = i >> 6;
    const int s    = rest % SLOTS;
    const int w    = rest / SLOTS;
    const int row  = w * 64 + l;
    const int col  = s - l;
    float4 r = make_float4(0.f, 0.f, 0.f, 0.f);
    if (col >= 0 && col < NDIM) {
      const float* tp = theta + ((size_t)row * NDIM + col) * 3;
      r.x = __expf(tp[0]); r.y = __expf(tp[1]); r.z = __expf(tp[2]);
    }
    g_S4[i] = r;
  }
}

// ---------------- prep B: sentinel/boundary init ---------------------------
__global__ void vit_prep_bnd() {
  const int tid = blockIdx.x * blockDim.x + threadIdx.x;
  const int stride = gridDim.x * blockDim.x;
  const int nb = (NBAND+1) * BCOLS;
  const u64 hi0 = ((u64)(unsigned)ENCB) << 32;   // (Y=0, e=0)
  for (int i = tid; i < nb; i += stride) {
    int w = i / BCOLS;
    int c = i - w * BCOLS;
    u64 lo, hi;
    if (c > NDIM)    { lo = 0ull; hi = hi0; }                                   // pad cols
    else if (w == 0) { lo = (c == 0) ? (u64)__float_as_uint(1.0f) : 0ull; hi = hi0; } // row 0
    else if (c == 0) { lo = 0ull; hi = hi0; }                                   // V[i,0] = -inf
    else             { lo = SENTV; hi = SENTV; }                                // to be produced
    ast(&g_B[(size_t)i*2],   lo);
    ast(&g_B[(size_t)i*2+1], hi);
  }
}

// ---------------- main: 16 waves x 2 interleaved bands, exp-space ----------
// Diagnosis (R1-R9): tau ~420cy/step invariant across 5 theta-staging schemes
// => single in-order wave is ILP/hazard-bound, not memory-bound. Fix: each
// wave runs TWO independent bands (A=2w, B=2w+1, B 5 blocks behind) with
// steps interleaved pairwise so each band's chain fills the other's stalls.
// All per-band machinery (validate/stage/ds-ring/STEP/rescale/warmup) is
// VERBATIM R9, suffix-parameterized.
__global__ void __launch_bounds__(64, 1)
__attribute__((amdgpu_waves_per_eu(1, 1)))
vit_main(const float* __restrict__ A, float* __restrict__ out) {
  __shared__ float4 sT[4096];   // 64KB: band A buffers [0,2048), band B [2048,4096)
  const int lane = threadIdx.x;
  const int w    = blockIdx.x;           // 0..15
  const bool isL0 = (lane == 0);
  const int lsel = lane & 15;
  const bool termB = (w == 15);

  const float a00 = __expf(A[0]), a01 = __expf(A[1]), a02 = __expf(A[2]);
  const float a10 = __expf(A[3]), a11 = __expf(A[4]), a12 = __expf(A[5]);
  const float a20 = __expf(A[6]), a21 = __expf(A[7]), a22 = __expf(A[8]);

  const int bA = 2*w, bB = 2*w + 1;
  const float4* tb4A = g_S4 + (size_t)bA * SLOTS * 64 + lane;
  const float4* tb4B = g_S4 + (size_t)bB * SLOTS * 64 + lane;
  u64* binA  = g_B + (size_t)bA     * BCOLS * 2;
  u64* boutA = g_B + (size_t)(bA+1) * BCOLS * 2;
  u64* binB  = boutA;
  u64* boutB = g_B + (size_t)(bB+1) * BCOLS * 2;

  float MpA=0.f,XpA=0.f,YpA=0.f, MuA=0.f,XuA=0.f,YuA=0.f, MudA=0.f,XudA=0.f,YudA=0.f;
  float MpB=0.f,XpB=0.f,YpB=0.f, MuB=0.f,XuB=0.f,YuB=0.f, MudB=0.f,XudB=0.f,YudB=0.f;
  int e_wA = 0, e_wB = 0, se_wA = 0, se_wB = 0;
  u64 cLoA=0, cHiA=0, cLoB=0, cHiB=0;
  float4 d0A, d1A, d2A, d3A, d0B, d1B, d2B, d3B;
  int baseA = 0, baseB = 0;
  u64* rpbA = binA + (size_t)(2 + lsel) * 2;
  u64* rpbB = binB + (size_t)(2 + lsel) * 2;

#define WARMUP(S, binp)                                                        \
  {                                                                            \
    u64 lo = ald(binp), hi = ald(binp + 1);                                    \
    while (lo == SENTV || hi == SENTV) { __builtin_amdgcn_s_sleep(2); lo = ald(binp); hi = ald(binp+1); } \
    if (isL0) { Mud##S = __uint_as_float((unsigned)lo);                        \
      Xud##S = __uint_as_float((unsigned)(lo >> 32));                          \
      Yud##S = __uint_as_float((unsigned)hi); }                                \
  }                                                                            \
  {                                                                            \
    u64 lo = ald(binp + 2), hi = ald(binp + 3);                                \
    while (lo == SENTV || hi == SENTV) { __builtin_amdgcn_s_sleep(8); lo = ald(binp+2); hi = ald(binp+3); } \
    int ep = (int)((unsigned)(hi >> 32) - (unsigned)ENCB);                     \
    int dd = ep - e_w##S;                                                      \
    if (__builtin_amdgcn_readfirstlane(dd) > 48) { e_w##S = ep; dd = 0; }      \
    if (isL0) { Mu##S = ldexpf(__uint_as_float((unsigned)lo), dd);             \
      Xu##S = ldexpf(__uint_as_float((unsigned)(lo >> 32)), dd);               \
      Yu##S = ldexpf(__uint_as_float((unsigned)hi), dd); }                     \
  }

#define VALIDATE(S)                                                            \
  cLo##S = ald(rpb##S); cHi##S = ald(rpb##S + 1);                              \
  { bool bad_ = (cLo##S == SENTV) || (cHi##S == SENTV);                        \
    while (__ballot(bad_)) {                                                   \
      __builtin_amdgcn_s_sleep(1);                                             \
      cLo##S = ald(rpb##S); cHi##S = ald(rpb##S + 1);                          \
      bad_ = (cLo##S == SENTV) || (cHi##S == SENTV);                           \
    } }                                                                        \
  se_w##S = __builtin_amdgcn_readfirstlane(e_w##S);

#define FENCE()                                                                \
  __builtin_amdgcn_s_waitcnt(0x0F70);  /* vmcnt(0) only */                     \
  __builtin_amdgcn_sched_barrier(0);

#define STAGE(S, BASEV, LDSDST)                                                \
  {                                                                            \
    const float4* tn_ = tb4##S + (size_t)((BASEV) + 16) * 64;                  \
    _Pragma("unroll")                                                          \
    for (int u_ = 0; u_ < 16; ++u_)                                            \
      gll16(tn_ + (size_t)u_ * 64, &sT[(LDSDST) + u_ * 64]);                   \
  }

#define DSPRO(S, LDSA)                                                         \
  d0##S = sT[(LDSA) + 0*64 + lane];                                            \
  d1##S = sT[(LDSA) + 1*64 + lane];                                            \
  d2##S = sT[(LDSA) + 2*64 + lane];                                            \
  d3##S = sT[(LDSA) + 3*64 + lane];

#define STEP(S, U, DV, TERM)                                                   \
  {                                                                            \
    const int s = base##S + (U) + 1;        /* lane computes col j = s-lane */ \
    float mn = DV.x * fmaf(a02, Yud##S, fmaf(a01, Xud##S, a00*Mud##S));        \
    float xn = DV.y * fmaf(a12, Yu##S,  fmaf(a11, Xu##S,  a10*Mu##S));         \
    float yn = DV.z * fmaf(a22, Yp##S,  fmaf(a21, Xp##S,  a20*Mp##S));         \
    if (s >= 64 && lane == 63) {                                               \
      u64 slo = ((u64)__float_as_uint(xn) << 32) | __float_as_uint(mn);        \
      u64 shi = ((u64)(unsigned)(e_w##S + ENCB) << 32) | __float_as_uint(yn);  \
      ast(bO##S + (size_t)(U)*2,     slo);                                     \
      ast(bO##S + (size_t)(U)*2 + 1, shi);                                     \
    }                                                                          \
    if ((TERM) && s == 2111 && lane == 63) {                                   \
      out[0] = (log2f(mn + xn + yn) + (float)e_w##S) * 0.69314718055994531f;   \
    }                                                                          \
    const int Mbb = __builtin_amdgcn_readlane((int)(unsigned)cLo##S, (U));     \
    const int Xbb = __builtin_amdgcn_readlane((int)(unsigned)(cLo##S >> 32), (U)); \
    const int Ybb = __builtin_amdgcn_readlane((int)(unsigned)cHi##S, (U));     \
    const int Ebb = __builtin_amdgcn_readlane((int)(unsigned)(cHi##S >> 32), (U)); \
    int dsv = (Ebb - ENCB) - se_w##S;                                          \
    if (dsv > 48) {                                                            \
      const int ep = Ebb - ENCB;                                               \
      const int sh = se_w##S - ep;                                             \
      mn = ldexpf(mn,sh); xn = ldexpf(xn,sh); yn = ldexpf(yn,sh);              \
      Mu##S = ldexpf(Mu##S,sh); Xu##S = ldexpf(Xu##S,sh); Yu##S = ldexpf(Yu##S,sh); \
      Mud##S= ldexpf(Mud##S,sh);Xud##S= ldexpf(Xud##S,sh);Yud##S= ldexpf(Yud##S,sh); \
      e_w##S = ep; se_w##S = ep; dsv = 0;                                      \
    }                                                                          \
    Mud##S = Mu##S; Xud##S = Xu##S; Yud##S = Yu##S;                            \
    const float sm = shup1(mn);                                                \
    const float sx = shup1(xn);                                                \
    const float sy = shup1(yn);                                                \
    Mu##S = isL0 ? ldexpf(__int_as_float(Mbb), dsv) : sm;                      \
    Xu##S = isL0 ? ldexpf(__int_as_float(Xbb), dsv) : sx;                      \
    Yu##S = isL0 ? ldexpf(__int_as_float(Ybb), dsv) : sy;                      \
    Mp##S = mn; Xp##S = xn; Yp##S = yn;                                        \
  }
#define STEPR(S, U, DV, TERM, LDSA) STEP(S, U, DV, TERM) DV = sT[(LDSA) + ((U)+4)*64 + lane];

#define RESCALE(S)                                                             \
  {                                                                            \
    float m = fmaxf(fmaxf(Mp##S, Xp##S), Yp##S);                               \
    const int jl = base##S + 16 - lane;                                        \
    if (jl < 1 || jl > NDIM) m = 0.0f;                                         \
    m = fmaxf(m, __shfl_xor(m, 1));                                            \
    m = fmaxf(m, __shfl_xor(m, 2));                                            \
    m = fmaxf(m, __shfl_xor(m, 4));                                            \
    m = fmaxf(m, __shfl_xor(m, 8));                                            \
    m = fmaxf(m, __shfl_xor(m, 16));                                           \
    m = fmaxf(m, __shfl_xor(m, 32));                                           \
    int E = (int)((__float_as_uint(m) >> 23) & 0xFF) - 127;                    \
    if (m == 0.0f) E = 0;                                                      \
    const int sh = -E;                                                         \
    Mp##S = ldexpf(Mp##S,sh); Xp##S = ldexpf(Xp##S,sh); Yp##S = ldexpf(Yp##S,sh); \
    Mu##S = ldexpf(Mu##S,sh); Xu##S = ldexpf(Xu##S,sh); Yu##S = ldexpf(Yu##S,sh); \
    Mud##S= ldexpf(Mud##S,sh);Xud##S= ldexpf(Xud##S,sh);Yud##S= ldexpf(Yud##S,sh); \
    e_w##S += E;                                                               \
  }

#define ABLOCK()                                                               \
  { const unsigned lA = ((unsigned)(baseA >> 4) & 1u) << 10;                   \
    VALIDATE(A) FENCE()                                                        \
    STAGE(A, baseA, lA ^ 1024u)                                                \
    __builtin_amdgcn_sched_barrier(0);                                         \
    DSPRO(A, lA)                                                               \
    u64* bOA = boutA + (size_t)(baseA - 62) * 2;                               \
    STEPR(A,0,d0A,false,lA)  STEPR(A,1,d1A,false,lA)                           \
    STEPR(A,2,d2A,false,lA)  STEPR(A,3,d3A,false,lA)                           \
    STEPR(A,4,d0A,false,lA)  STEPR(A,5,d1A,false,lA)                           \
    STEPR(A,6,d2A,false,lA)  STEPR(A,7,d3A,false,lA)                           \
    STEPR(A,8,d0A,false,lA)  STEPR(A,9,d1A,false,lA)                           \
    STEPR(A,10,d2A,false,lA) STEPR(A,11,d3A,false,lA)                          \
    STEP(A,12,d0A,false) STEP(A,13,d1A,false)                                  \
    STEP(A,14,d2A,false) STEP(A,15,d3A,false)                                  \
    RESCALE(A)                                                                 \
    baseA += 16; rpbA += 32; }

#define BBLOCK()                                                               \
  { const unsigned lB = 2048u + (((unsigned)(baseB >> 4) & 1u) << 10);         \
    VALIDATE(B) FENCE()                                                        \
    STAGE(B, baseB, lB ^ 1024u)                                                \
    __builtin_amdgcn_sched_barrier(0);                                         \
    DSPRO(B, lB)                                                               \
    u64* bOB = boutB + (size_t)(baseB - 62) * 2;                               \
    STEPR(B,0,d0B,termB,lB)  STEPR(B,1,d1B,termB,lB)                           \
    STEPR(B,2,d2B,termB,lB)  STEPR(B,3,d3B,termB,lB)                           \
    STEPR(B,4,d0B,termB,lB)  STEPR(B,5,d1B,termB,lB)                           \
    STEPR(B,6,d2B,termB,lB)  STEPR(B,7,d3B,termB,lB)                           \
    STEPR(B,8,d0B,termB,lB)  STEPR(B,9,d1B,termB,lB)                           \
    STEPR(B,10,d2B,termB,lB) STEPR(B,11,d3B,termB,lB)                          \
    STEP(B,12,d0B,termB) STEP(B,13,d1B,termB)                                  \
    STEP(B,14,d2B,termB) STEP(B,15,d3B,termB)                                  \
    RESCALE(B)                                                                 \
    baseB += 16; rpbB += 32; }

  // ---- prologue: stage A block 0, warm up A, run 5 A-only blocks ----
  {
    _Pragma("unroll")
    for (int u_ = 0; u_ < 16; ++u_)
      gll16(tb4A + (size_t)u_ * 64, &sT[u_ * 64]);
  }
  WARMUP(A, binA)
  for (int i = 0; i < 5; ++i) { ABLOCK() }

  // ---- B prologue: stage B block 0, warm up B (A cols 0..17 now exist) ----
  {
    _Pragma("unroll")
    for (int u_ = 0; u_ < 16; ++u_)
      gll16(tb4B + (size_t)u_ * 64, &sT[2048 + u_ * 64]);
  }
  WARMUP(B, binB)

  // ---- main: 127 iterations, A and B step-interleaved ----
  for (int i = 0; i < 127; ++i) {
    const unsigned lA = ((unsigned)(baseA >> 4) & 1u) << 10;
    const unsigned lB = 2048u + (((unsigned)(baseB >> 4) & 1u) << 10);
    VALIDATE(A) VALIDATE(B)
    FENCE()
    STAGE(A, baseA, lA ^ 1024u)
    STAGE(B, baseB, lB ^ 1024u)
    __builtin_amdgcn_sched_barrier(0);
    DSPRO(A, lA) DSPRO(B, lB)
    u64* bOA = boutA + (size_t)(baseA - 62) * 2;
    u64* bOB = boutB + (size_t)(baseB - 62) * 2;
    STEPR(A,0,d0A,false,lA)   STEPR(B,0,d0B,termB,lB)
    STEPR(A,1,d1A,false,lA)   STEPR(B,1,d1B,termB,lB)
    STEPR(A,2,d2A,false,lA)   STEPR(B,2,d2B,termB,lB)
    STEPR(A,3,d3A,false,lA)   STEPR(B,3,d3B,termB,lB)
    STEPR(A,4,d0A,false,lA)   STEPR(B,4,d0B,termB,lB)
    STEPR(A,5,d1A,false,lA)   STEPR(B,5,d1B,termB,lB)
    STEPR(A,6,d2A,false,lA)   STEPR(B,6,d2B,termB,lB)
    STEPR(A,7,d3A,false,lA)   STEPR(B,7,d3B,termB,lB)
    STEPR(A,8,d0A,false,lA)   STEPR(B,8,d0B,termB,lB)
    STEPR(A,9,d1A,false,lA)   STEPR(B,9,d1B,termB,lB)
    STEPR(A,10,d2A,false,lA)  STEPR(B,10,d2B,termB,lB)
    STEPR(A,11,d3A,false,lA)  STEPR(B,11,d3B,termB,lB)
    STEP(A,12,d0A,false)      STEP(B,12,d0B,termB)
    STEP(A,13,d1A,false)      STEP(B,13,d1B,termB)
    STEP(A,14,d2A,false)      STEP(B,14,d2B,termB)
    STEP(A,15,d3A,false)      STEP(B,15,d3B,termB)
    RESCALE(A) RESCALE(B)
    baseA += 16; baseB += 16; rpbA += 32; rpbB += 32;
  }

  // ---- epilogue: 5 B-only blocks (B blocks 127..131; terminal at s=2111) ----
  for (int i = 0; i < 5; ++i) { BBLOCK() }

#undef ABLOCK
#undef BBLOCK
#undef RESCALE
#undef STEPR
#undef STEP
#undef DSPRO
#undef STAGE
#undef FENCE
#undef VALIDATE
#undef WARMUP
}

extern "C" void kernel_launch(void* const* d_in, const int* in_sizes, int n_in,
                              void* d_out, int out_size, void* d_ws, size_t ws_size,
                              hipStream_t stream) {
  const float* theta = (const float*)d_in[0];
  const float* A     = (const float*)d_in[1];
  float* out = (float*)d_out;
  (void)in_sizes; (void)n_in; (void)out_size; (void)d_ws; (void)ws_size;
  vit_prep_theta<<<dim3(8192), dim3(256), 0, stream>>>(theta);
  vit_prep_bnd<<<dim3(256), dim3(256), 0, stream>>>();
  vit_main<<<dim3(16), dim3(64), 0, stream>>>(A, out);
}

// Round 11
// 668.866 us; speedup vs baseline: 2.3412x; 2.3412x over previous
//
#include <hip/hip_runtime.h>

#define NDIM  2048
#define WAVES 32
#define BCOLS 2176            // 0..2048 valid + pad
#define SLOTS 2128            // 2112 steps + pad
#define ENCB  0x40000000
#define SENTV 0xFFFFFFFFFFFFFFFFull

typedef unsigned long long u64;

// Static scratch: prep kernels rewrite everything main relies on, every launch.
// g_S4[w][sidx][lane] = {exp theta[w*64+lane][sidx-lane][0..2], 0}
__device__ __align__(16) float4 g_S4[(size_t)WAVES * SLOTS * 64];
__device__ __align__(16) u64    g_B[(size_t)(WAVES+1) * BCOLS * 2]; // boundary handoff

__device__ __forceinline__ u64 ald(const u64* p) {
  return __hip_atomic_load(p, __ATOMIC_RELAXED, __HIP_MEMORY_SCOPE_AGENT);
}
__device__ __forceinline__ void ast(u64* p, u64 v) {
  __hip_atomic_store(p, v, __ATOMIC_RELAXED, __HIP_MEMORY_SCOPE_AGENT);
}
// shift-up-by-1 across the wave via DPP wave_shr1. Lane 0 receives 0 and is
// overwritten by the boundary select.
__device__ __forceinline__ float shup1(float x) {
  int v = __builtin_amdgcn_update_dpp(0, __float_as_int(x), 0x138, 0xf, 0xf, false);
  return __int_as_float(v);
}
__device__ __forceinline__ int imax(int a, int b) { return a > b ? a : b; }

// ---------------- prep A: exp(theta) transposed into staircase order --------
__global__ void vit_prep_theta(const float* __restrict__ theta) {
  const int tid = blockIdx.x * blockDim.x + threadIdx.x;
  const int stride = gridDim.x * blockDim.x;
  const int total = WAVES * SLOTS * 64;
  for (int i = tid; i < total; i += stride) {
    const int l    = i & 63;
    const int rest = i >> 6;
    const int s    = rest % SLOTS;
    const int w    = rest / SLOTS;
    const int row  = w * 64 + l;
    const int col  = s - l;
    float4 r = make_float4(0.f, 0.f, 0.f, 0.f);
    if (col >= 0 && col < NDIM) {
      const float* tp = theta + ((size_t)row * NDIM + col) * 3;
      r.x = __expf(tp[0]); r.y = __expf(tp[1]); r.z = __expf(tp[2]);
    }
    g_S4[i] = r;
  }
}

// ---------------- prep B: sentinel/boundary init ---------------------------
__global__ void vit_prep_bnd() {
  const int tid = blockIdx.x * blockDim.x + threadIdx.x;
  const int stride = gridDim.x * blockDim.x;
  const int nb = (WAVES+1) * BCOLS;
  const u64 hi0 = ((u64)(unsigned)ENCB) << 32;   // (Y=0, e=0)
  for (int i = tid; i < nb; i += stride) {
    int w = i / BCOLS;
    int c = i - w * BCOLS;
    u64 lo, hi;
    if (c > NDIM)    { lo = 0ull; hi = hi0; }                                   // pad cols
    else if (w == 0) { lo = (c == 0) ? (u64)__float_as_uint(1.0f) : 0ull; hi = hi0; } // row 0
    else if (c == 0) { lo = 0ull; hi = hi0; }                                   // V[i,0] = -inf
    else             { lo = SENTV; hi = SENTV; }                                // to be produced
    ast(&g_B[(size_t)i*2],   lo);
    ast(&g_B[(size_t)i*2+1], hi);
  }
}

// ---------------- main: 32 waves, striped wavefront, exp-space -------------
// R4 structure (best measured, 677us) + instruction diet:
//  - per-BLOCK boundary scale prep, adopt threshold dm>0 => injected scale
//    ds' <= 0 ALWAYS (injection can never inflate -> the R6/R7 inf mode is
//    structurally impossible). Per-step scale cost: 3 readlane + 3 cndmask.
//  - handoff-store `s>=64` check only in blocks 0..3; terminal check only in
//    final block instantiation.
__global__ void __launch_bounds__(64, 1)
__attribute__((amdgpu_waves_per_eu(1, 1)))
vit_main(const float* __restrict__ A, float* __restrict__ out) {
  const int lane = threadIdx.x;
  const int w    = blockIdx.x;
  const bool isL0 = (lane == 0);
  const int lsel = lane & 15;

  const float a00 = __expf(A[0]), a01 = __expf(A[1]), a02 = __expf(A[2]);
  const float a10 = __expf(A[3]), a11 = __expf(A[4]), a12 = __expf(A[5]);
  const float a20 = __expf(A[6]), a21 = __expf(A[7]), a22 = __expf(A[8]);

  const float4* tb4 = g_S4 + (size_t)w * SLOTS * 64 + lane;
  u64* bin  = g_B + (size_t)w     * BCOLS * 2;
  u64* bout = g_B + (size_t)(w+1) * BCOLS * 2;

  // state: own row col j-1 (p), row-above col j (u), row-above col j-1 (ud)
  float Mp=0.f,Xp=0.f,Yp=0.f, Mu=0.f,Xu=0.f,Yu=0.f, Mud=0.f,Xud=0.f,Yud=0.f;
  int e_w = 0;   // wave scale: registers hold value * 2^-e_w (wave-uniform)

  // ---- theta block 0 (slots 0..15) into named regs ----
  float4 Ta0  = tb4[0*64],  Ta1  = tb4[1*64],  Ta2  = tb4[2*64],  Ta3  = tb4[3*64];
  float4 Ta4  = tb4[4*64],  Ta5  = tb4[5*64],  Ta6  = tb4[6*64],  Ta7  = tb4[7*64];
  float4 Ta8  = tb4[8*64],  Ta9  = tb4[9*64],  Ta10 = tb4[10*64], Ta11 = tb4[11*64];
  float4 Ta12 = tb4[12*64], Ta13 = tb4[13*64], Ta14 = tb4[14*64], Ta15 = tb4[15*64];
  float4 Tb0  = make_float4(0,0,0,0), Tb1  = Tb0, Tb2  = Tb0, Tb3  = Tb0;
  float4 Tb4  = Tb0, Tb5  = Tb0, Tb6  = Tb0, Tb7  = Tb0;
  float4 Tb8  = Tb0, Tb9  = Tb0, Tb10 = Tb0, Tb11 = Tb0;
  float4 Tb12 = Tb0, Tb13 = Tb0, Tb14 = Tb0, Tb15 = Tb0;

  // ---- boundary ring: lane-striped. Block k group = cols k*16+2..k*16+17,
  //      lane u (=lsel) holds col k*16+2+u. Preload block 0; rpn -> block 1.
  u64 cLoa, cHia, cLob = 0, cHib = 0;
  u64* rpn;
  {
    u64* rp0 = bin + (size_t)(2 + lsel) * 2;
    cLoa = ald(rp0); cHia = ald(rp0 + 1);
    rpn = rp0 + 32;
  }

  // col 0 -> ud (prefilled, never sentinel)
  {
    u64 lo = ald(bin), hi = ald(bin + 1);
    while (lo == SENTV || hi == SENTV) { __builtin_amdgcn_s_sleep(2); lo = ald(bin); hi = ald(bin+1); }
    if (isL0) {
      Mud = __uint_as_float((unsigned)lo);
      Xud = __uint_as_float((unsigned)(lo >> 32));
      Yud = __uint_as_float((unsigned)hi);
    }
  }
  // col 1 -> u (spin = pipeline fill)
  {
    u64 lo = ald(bin + 2), hi = ald(bin + 3);
    while (lo == SENTV || hi == SENTV) { __builtin_amdgcn_s_sleep(8); lo = ald(bin+2); hi = ald(bin+3); }
    int ep = (int)((unsigned)(hi >> 32) - (unsigned)ENCB);
    int dd = ep - e_w;
    if (__builtin_amdgcn_readfirstlane(dd) > 48) { e_w = ep; dd = 0; } // states are zero
    if (isL0) {
      Mu = ldexpf(__uint_as_float((unsigned)lo), dd);
      Xu = ldexpf(__uint_as_float((unsigned)(lo >> 32)), dd);
      Yu = ldexpf(__uint_as_float((unsigned)hi), dd);
    }
  }

// STEP: SM=1 -> store unconditionally on lane63; SM=0 -> check s>=64.
// TM=1 -> terminal check (final block only).
#define STEP(U, S, SM, TM)                                                     \
  {                                                                            \
    const int s = base + (U) + 1;           /* lane computes col j = s-lane */ \
    float mn = T##S##U.x * fmaf(a02, Yud, fmaf(a01, Xud, a00*Mud));            \
    float xn = T##S##U.y * fmaf(a12, Yu,  fmaf(a11, Xu,  a10*Mu));             \
    float yn = T##S##U.z * fmaf(a22, Yp,  fmaf(a21, Xp,  a20*Mp));             \
    if ((SM) ? (lane == 63) : (s >= 64 && lane == 63)) {                       \
      u64 slo = ((u64)__float_as_uint(xn) << 32) | __float_as_uint(mn);        \
      u64 shi = ((u64)(unsigned)(e_w + ENCB) << 32) | __float_as_uint(yn);     \
      ast(bO + (size_t)(U)*2,     slo);                                        \
      ast(bO + (size_t)(U)*2 + 1, shi);                                        \
    }                                                                          \
    if ((TM) && s == 2111 && w == 31 && lane == 63) {                          \
      out[0] = (log2f(mn + xn + yn) + (float)e_w) * 0.69314718055994531f;      \
    }                                                                          \
    /* boundary consume for col s+1: pre-scaled stripe, lane (U) -> SGPR */    \
    const float rM = __int_as_float(__builtin_amdgcn_readlane(__float_as_int(Mbf), (U))); \
    const float rX = __int_as_float(__builtin_amdgcn_readlane(__float_as_int(Xbf), (U))); \
    const float rY = __int_as_float(__builtin_amdgcn_readlane(__float_as_int(Ybf), (U))); \
    /* rotate */                                                               \
    Mud = Mu; Xud = Xu; Yud = Yu;                                              \
    const float sm = shup1(mn);                                                \
    const float sx = shup1(xn);                                                \
    const float sy = shup1(yn);                                                \
    Mu = isL0 ? rM : sm;                                                       \
    Xu = isL0 ? rX : sx;                                                       \
    Yu = isL0 ? rY : sy;                                                       \
    Mp = mn; Xp = xn; Yp = yn;                                                 \
  }

#define BLOCK(S, SN, SM, TM)                                                   \
  {                                                                            \
    /* ---- validate ring S (cols base+2 .. base+17, striped) ---- */          \
    u64* rpc_ = rpn - 32;                                                      \
    bool bad_ = (cLo##S == SENTV) || (cHi##S == SENTV);                        \
    while (__ballot(bad_)) {                                                   \
      __builtin_amdgcn_s_sleep(1);                                             \
      cLo##S = ald(rpc_); cHi##S = ald(rpc_ + 1);                              \
      bad_ = (cLo##S == SENTV) || (cHi##S == SENTV);                           \
    }                                                                          \
    /* ---- stage block k+1 theta into the other reg set ---- */               \
    {                                                                          \
      const float4* tn_ = tb4 + (size_t)(base + 16) * 64;                      \
      T##SN##0  = tn_[0*64];  T##SN##1  = tn_[1*64];                           \
      T##SN##2  = tn_[2*64];  T##SN##3  = tn_[3*64];                           \
      T##SN##4  = tn_[4*64];  T##SN##5  = tn_[5*64];                           \
      T##SN##6  = tn_[6*64];  T##SN##7  = tn_[7*64];                           \
      T##SN##8  = tn_[8*64];  T##SN##9  = tn_[9*64];                           \
      T##SN##10 = tn_[10*64]; T##SN##11 = tn_[11*64];                          \
      T##SN##12 = tn_[12*64]; T##SN##13 = tn_[13*64];                          \
      T##SN##14 = tn_[14*64]; T##SN##15 = tn_[15*64];                          \
    }                                                                          \
    cLo##SN = ald(rpn); cHi##SN = ald(rpn + 1);                                \
    rpn += 32;                                                                 \
    /* ---- per-BLOCK scale prep: adopt if dm>0 => injected ds' <= 0 ---- */   \
    int dsl = ((int)(unsigned)(cHi##S >> 32) - ENCB) - e_w;                    \
    int dm = dsl;                                                              \
    dm = imax(dm, __shfl_xor(dm, 1));                                          \
    dm = imax(dm, __shfl_xor(dm, 2));                                          \
    dm = imax(dm, __shfl_xor(dm, 4));                                          \
    dm = imax(dm, __shfl_xor(dm, 8));   /* uniform (lanes 16+ replicate) */    \
    if (dm > 0) {                                                              \
      const int sh = -dm;                                                      \
      Mp = ldexpf(Mp,sh); Xp = ldexpf(Xp,sh); Yp = ldexpf(Yp,sh);              \
      Mu = ldexpf(Mu,sh); Xu = ldexpf(Xu,sh); Yu = ldexpf(Yu,sh);              \
      Mud= ldexpf(Mud,sh);Xud= ldexpf(Xud,sh);Yud= ldexpf(Yud,sh);             \
      e_w += dm; dsl -= dm;                                                    \
    }                                                                          \
    const float Mbf = ldexpf(__uint_as_float((unsigned)cLo##S), dsl);          \
    const float Xbf = ldexpf(__uint_as_float((unsigned)(cLo##S >> 32)), dsl);  \
    const float Ybf = ldexpf(__uint_as_float((unsigned)cHi##S), dsl);          \
    __builtin_amdgcn_sched_barrier(0);                                         \
    /* ---- 16 steps ---- */                                                   \
    u64* bO = bout + (size_t)(base - 62) * 2;                                  \
    STEP(0,S,SM,TM)  STEP(1,S,SM,TM)  STEP(2,S,SM,TM)  STEP(3,S,SM,TM)         \
    STEP(4,S,SM,TM)  STEP(5,S,SM,TM)  STEP(6,S,SM,TM)  STEP(7,S,SM,TM)         \
    STEP(8,S,SM,TM)  STEP(9,S,SM,TM)  STEP(10,S,SM,TM) STEP(11,S,SM,TM)        \
    STEP(12,S,SM,TM) STEP(13,S,SM,TM) STEP(14,S,SM,TM) STEP(15,S,SM,TM)        \
    /* ---- epoch rescale (wave-uniform, exact power-of-2) ---- */             \
    {                                                                          \
      float m = fmaxf(fmaxf(Mp, Xp), Yp);                                      \
      const int jl = base + 16 - lane;                                         \
      if (jl < 1 || jl > NDIM) m = 0.0f;                                       \
      m = fmaxf(m, __shfl_xor(m, 1));                                          \
      m = fmaxf(m, __shfl_xor(m, 2));                                          \
      m = fmaxf(m, __shfl_xor(m, 4));                                          \
      m = fmaxf(m, __shfl_xor(m, 8));                                          \
      m = fmaxf(m, __shfl_xor(m, 16));                                         \
      m = fmaxf(m, __shfl_xor(m, 32));                                         \
      int E = (int)((__float_as_uint(m) >> 23) & 0xFF) - 127;                  \
      if (m == 0.0f) E = 0;                                                    \
      const int sh = -E;                                                       \
      Mp = ldexpf(Mp,sh); Xp = ldexpf(Xp,sh); Yp = ldexpf(Yp,sh);              \
      Mu = ldexpf(Mu,sh); Xu = ldexpf(Xu,sh); Yu = ldexpf(Yu,sh);              \
      Mud= ldexpf(Mud,sh);Xud= ldexpf(Xud,sh);Yud= ldexpf(Yud,sh);             \
      e_w += E;                                                                \
    }                                                                          \
    base += 16;                                                                \
  }

  int base = 0;
  // blocks 0..3: s>=64 store check active
  BLOCK(a, b, 0, 0) BLOCK(b, a, 0, 0)
  BLOCK(a, b, 0, 0) BLOCK(b, a, 0, 0)
  // blocks 4..129: unconditional lane-63 store
  for (int it = 0; it < 63; ++it) {
    BLOCK(a, b, 1, 0)
    BLOCK(b, a, 1, 0)
  }
  // blocks 130, 131: final pair; terminal check only in block 131
  BLOCK(a, b, 1, 0)
  BLOCK(b, a, 1, 1)
#undef BLOCK
#undef STEP
}

extern "C" void kernel_launch(void* const* d_in, const int* in_sizes, int n_in,
                              void* d_out, int out_size, void* d_ws, size_t ws_size,
                              hipStream_t stream) {
  const float* theta = (const float*)d_in[0];
  const float* A     = (const float*)d_in[1];
  float* out = (float*)d_out;
  (void)in_sizes; (void)n_in; (void)out_size; (void)d_ws; (void)ws_size;
  vit_prep_theta<<<dim3(8192), dim3(256), 0, stream>>>(theta);
  vit_prep_bnd<<<dim3(256), dim3(256), 0, stream>>>();
  vit_main<<<dim3(WAVES), dim3(64), 0, stream>>>(A, out);
}